// Round 2
// baseline (370.936 us; speedup 1.0000x reference)
//
#include <hip/hip_runtime.h>

#define N_NODES 100000
#define N_EDGES 1600000
#define D_IN    128
#define D_OUT   64

#define SCAN1_BLOCKS 391        // ceil(100000/256)
#define XT_STRIDE 260           // padded row-count stride: 16B-aligned, low conflicts
#define GROUPS 8                // one row-range group per XCD
#define ROWS_PER_GROUP 12500    // 8 groups of 12500 rows
#define BPG 48                  // blocks per group (count/place slicing)
#define R_PAD 12544             // padded per-(group,block) row stride (even, 64-mult)
typedef unsigned long long ull;

// ---------------------------------------------------------------------------
// Kernel A: support = X @ W (fp32). Register-tiled LDS GEMM.
// Block = 256 threads -> 256 rows x 64 cols, 8x8 per thread.
// ---------------------------------------------------------------------------
__global__ __launch_bounds__(256) void gcn_gemm(
    const float* __restrict__ x,        // [N, 128]
    const float* __restrict__ w,        // [128, 64]
    float* __restrict__ support)        // [N, 64]
{
    __shared__ float wl[D_IN * D_OUT];      // [k][col], 32 KB
    __shared__ float xT[32 * XT_STRIDE];    // [k_local][row], 33.3 KB

    const int t  = threadIdx.x;
    const int tx = t & 7;                   // col group: cols tx*8 .. tx*8+7
    const int ty = t >> 3;                  // row group: rows ty*8 .. ty*8+7 (0..31)
    const long row0 = (long)blockIdx.x * 256;

    // stage full W once (coalesced float4)
    {
        const float4* wf  = (const float4*)w;
        float4*       wlf = (float4*)wl;
#pragma unroll
        for (int j = 0; j < 8; ++j)
            wlf[t + 256 * j] = wf[t + 256 * j];
    }

    float acc[8][8];
#pragma unroll
    for (int i = 0; i < 8; ++i)
#pragma unroll
        for (int j = 0; j < 8; ++j)
            acc[i][j] = 0.f;

    for (int kc = 0; kc < 4; ++kc) {
        const int k0 = kc * 32;
        __syncthreads();                    // xT readers from prev chunk done

        // stage x chunk transposed: rows row0..row0+255, k in [k0, k0+32)
        const int kk = tx * 4;              // local k base 0,4,...,28
#pragma unroll
        for (int it = 0; it < 8; ++it) {
            const int  rg   = it * 32 + ty; // 0..255
            const long grow = row0 + rg;
            float4 v = make_float4(0.f, 0.f, 0.f, 0.f);
            if (grow < N_NODES)
                v = *(const float4*)&x[grow * D_IN + k0 + kk];
            xT[(kk + 0) * XT_STRIDE + rg] = v.x;
            xT[(kk + 1) * XT_STRIDE + rg] = v.y;
            xT[(kk + 2) * XT_STRIDE + rg] = v.z;
            xT[(kk + 3) * XT_STRIDE + rg] = v.w;
        }
        __syncthreads();

#pragma unroll 8
        for (int k = 0; k < 32; ++k) {
            const float4 a0 = *(const float4*)&xT[k * XT_STRIDE + ty * 8];
            const float4 a1 = *(const float4*)&xT[k * XT_STRIDE + ty * 8 + 4];
            const float4 b0 = *(const float4*)&wl[(k0 + k) * D_OUT + tx * 8];
            const float4 b1 = *(const float4*)&wl[(k0 + k) * D_OUT + tx * 8 + 4];
            const float av[8] = {a0.x, a0.y, a0.z, a0.w, a1.x, a1.y, a1.z, a1.w};
            const float bv[8] = {b0.x, b0.y, b0.z, b0.w, b1.x, b1.y, b1.z, b1.w};
#pragma unroll
            for (int i = 0; i < 8; ++i)
#pragma unroll
                for (int j = 0; j < 8; ++j)
                    acc[i][j] = fmaf(av[i], bv[j], acc[i][j]);
        }
    }

    // store 8 rows x 8 cols per thread (2 x float4 per row)
#pragma unroll
    for (int i = 0; i < 8; ++i) {
        const long r = row0 + ty * 8 + i;
        if (r < N_NODES) {
            float4 o0 = make_float4(acc[i][0], acc[i][1], acc[i][2], acc[i][3]);
            float4 o1 = make_float4(acc[i][4], acc[i][5], acc[i][6], acc[i][7]);
            *(float4*)&support[r * D_OUT + tx * 8]     = o0;
            *(float4*)&support[r * D_OUT + tx * 8 + 4] = o1;
        }
    }
}

// ---------------------------------------------------------------------------
// CSR build -- ZERO global atomics.
// (Round-1 evidence: 1.6M device-scope atomicAdds in k_count cost 67.7us with
//  WRITE_SIZE=56MB vs 6.4MB payload -- each atomic is a ~32B RMW at the
//  coherence point. Replaced by row-partitioned LDS histograms.)
//
// k_count2: block (g,b): g = XCD-aligned row group (12500 rows), b = edge
// slice index. Packed-u16 LDS histogram (25KB), LDS atomics only. Per-block
// counts dumped coalesced (u32) to sub[(g*BPG+b)][.] -- u16 is safe: max
// per-row degree << 65536.
// ---------------------------------------------------------------------------
__global__ __launch_bounds__(256) void k_count2(
    const int* __restrict__ rows, unsigned short* __restrict__ sub)
{
    __shared__ unsigned hist[R_PAD / 2];    // packed 2x u16 per word, 25.1 KB
    const int g   = blockIdx.x & 7;
    const int b   = blockIdx.x >> 3;
    const int rlo = g * ROWS_PER_GROUP;

    for (int i = threadIdx.x; i < R_PAD / 2; i += 256) hist[i] = 0u;
    __syncthreads();

    for (int base = b * 256; base < N_EDGES; base += BPG * 256) {
        const int r = rows[base + threadIdx.x] - rlo;   // E%256==0 -> in bounds
        if ((unsigned)r < ROWS_PER_GROUP)
            atomicAdd(&hist[r >> 1], 1u << ((r & 1) * 16));
    }
    __syncthreads();

    unsigned* dst = (unsigned*)&sub[(size_t)(g * BPG + b) * R_PAD];
    for (int i = threadIdx.x; i < R_PAD / 2; i += 256) dst[i] = hist[i];
}

// ---------------------------------------------------------------------------
// k_merge: per row, exclusive prefix over the 48 per-block counts (in place)
// + total -> counts[r]. One thread per row; fully coalesced u16 columns.
// Writes ALL of counts[] -> the counts memset is gone.
// ---------------------------------------------------------------------------
__global__ __launch_bounds__(256) void k_merge(
    unsigned short* __restrict__ sub, int* __restrict__ counts)
{
    const int r = blockIdx.x * 256 + threadIdx.x;
    if (r >= N_NODES) return;
    const int g = r / ROWS_PER_GROUP;
    const int i = r - g * ROWS_PER_GROUP;
    unsigned short* col = &sub[(size_t)g * BPG * R_PAD + i];
    int run = 0;
#pragma unroll 4
    for (int b = 0; b < BPG; ++b) {
        const int v = col[(size_t)b * R_PAD];
        col[(size_t)b * R_PAD] = (unsigned short)run;
        run += v;
    }
    counts[r] = run;
}

// phase 1: per-block exclusive scan of counts -> offsets, block totals -> bsum
__global__ __launch_bounds__(256) void k_scan1(
    const int* __restrict__ counts, int* __restrict__ offsets,
    int* __restrict__ bsum)
{
    __shared__ int s[256];
    const int t = threadIdx.x;
    const int i = blockIdx.x * 256 + t;
    const int v = (i < N_NODES) ? counts[i] : 0;
    s[t] = v;
    __syncthreads();
#pragma unroll
    for (int off = 1; off < 256; off <<= 1) {
        const int add = (t >= off) ? s[t - off] : 0;
        __syncthreads();
        s[t] += add;
        __syncthreads();
    }
    if (i < N_NODES) offsets[i] = s[t] - v;          // exclusive
    if (t == 255) bsum[blockIdx.x] = s[255];
}

// phase 2: exclusive scan of 391 block sums (single block of 512)
__global__ __launch_bounds__(512) void k_scan2(int* __restrict__ bsum)
{
    __shared__ int s[512];
    const int t = threadIdx.x;
    const int v = (t < SCAN1_BLOCKS) ? bsum[t] : 0;
    s[t] = v;
    __syncthreads();
#pragma unroll
    for (int off = 1; off < 512; off <<= 1) {
        const int add = (t >= off) ? s[t - off] : 0;
        __syncthreads();
        s[t] += add;
        __syncthreads();
    }
    if (t < SCAN1_BLOCKS) bsum[t] = s[t] - v;        // exclusive
}

// phase 3: add block base
__global__ __launch_bounds__(256) void k_scan3(
    int* __restrict__ offsets, const int* __restrict__ bsum)
{
    const int i = blockIdx.x * 256 + threadIdx.x;
    if (i < N_NODES)
        offsets[i] += bsum[blockIdx.x];
}

// ---------------------------------------------------------------------------
// k_place2: block (g,b) re-scans EXACTLY the slice it counted. LDS cursor
// cur[i] = offsets[rlo+i] + sub[(g*BPG+b)][i]; per-edge position via LDS
// atomicAdd (ds_add_rtn -- bank op, no fabric traffic). Pairs writes stay
// XCD-local per group, so lines assemble in one L2 before writeback.
// ---------------------------------------------------------------------------
__global__ __launch_bounds__(256) void k_place2(
    const int* __restrict__ rows, const int* __restrict__ cols,
    const float* __restrict__ vals, const int* __restrict__ offsets,
    const unsigned short* __restrict__ sub, ull* __restrict__ pairs)
{
    __shared__ int cur[ROWS_PER_GROUP];     // 50 KB
    const int g   = blockIdx.x & 7;
    const int b   = blockIdx.x >> 3;
    const int rlo = g * ROWS_PER_GROUP;
    const unsigned short* mysub = &sub[(size_t)(g * BPG + b) * R_PAD];

    for (int i = threadIdx.x; i < ROWS_PER_GROUP; i += 256)
        cur[i] = offsets[rlo + i] + (int)mysub[i];
    __syncthreads();

    for (int base = b * 256; base < N_EDGES; base += BPG * 256) {
        const int e = base + threadIdx.x;
        const int r = rows[e] - rlo;
        if ((unsigned)r < ROWS_PER_GROUP) {
            const int pos = atomicAdd(&cur[r], 1);
            pairs[pos] = ((ull)__float_as_uint(vals[e]) << 32) | (unsigned)cols[e];
        }
    }
}

// ---------------------------------------------------------------------------
// Segmented row sum + fused PReLU. One wave per row, lane = column.
// 8-wide unroll -> 8 independent 256B gathers in flight per wave.
// ---------------------------------------------------------------------------
__global__ __launch_bounds__(256) void k_rowsum(
    const int* __restrict__ offsets, const int* __restrict__ counts,
    const ull* __restrict__ pairs, const float* __restrict__ support,
    const float* __restrict__ prelu_a, float* __restrict__ out)
{
    const int lane = threadIdx.x & 63;
    const int row  = blockIdx.x * 4 + (threadIdx.x >> 6);  // grid exact: N%4==0

    const int start = offsets[row];
    const int deg   = counts[row];

    float acc = 0.f;
    int j = 0;
    for (; j + 8 <= deg; j += 8) {
        ull p[8];
#pragma unroll
        for (int u = 0; u < 8; ++u) p[u] = pairs[start + j + u];
        float s[8];
#pragma unroll
        for (int u = 0; u < 8; ++u)
            s[u] = support[(size_t)(unsigned)(p[u] & 0xffffffffu) * D_OUT + lane];
#pragma unroll
        for (int u = 0; u < 8; ++u)
            acc = fmaf(__uint_as_float((unsigned)(p[u] >> 32)), s[u], acc);
    }
    for (; j + 4 <= deg; j += 4) {
        ull p[4];
#pragma unroll
        for (int u = 0; u < 4; ++u) p[u] = pairs[start + j + u];
        float s[4];
#pragma unroll
        for (int u = 0; u < 4; ++u)
            s[u] = support[(size_t)(unsigned)(p[u] & 0xffffffffu) * D_OUT + lane];
#pragma unroll
        for (int u = 0; u < 4; ++u)
            acc = fmaf(__uint_as_float((unsigned)(p[u] >> 32)), s[u], acc);
    }
    for (; j < deg; ++j) {
        const ull p = pairs[start + j];
        const float s = support[(size_t)(unsigned)(p & 0xffffffffu) * D_OUT + lane];
        acc = fmaf(__uint_as_float((unsigned)(p >> 32)), s, acc);
    }

    const float a = prelu_a[0];
    out[(size_t)row * D_OUT + lane] = acc > 0.f ? acc : a * acc;
}

// ---------------------------------------------------------------------------
extern "C" void kernel_launch(void* const* d_in, const int* in_sizes, int n_in,
                              void* d_out, int out_size, void* d_ws, size_t ws_size,
                              hipStream_t stream) {
    const float* x    = (const float*)d_in[0];
    const int*   rows = (const int*)d_in[1];
    const int*   cols = (const int*)d_in[2];
    const float* vals = (const float*)d_in[3];
    const float* w    = (const float*)d_in[4];
    const float* pa   = (const float*)d_in[5];

    float* out     = (float*)d_out;                    // [N*64] PReLU output
    float* support = out + (size_t)N_NODES * D_OUT;    // [N*64] support (tuple elem 1)

    // workspace layout (~23.2 MB)
    int* counts  = (int*)d_ws;                         // 100032
    int* offsets = counts  + 100032;                   // 100032
    int* bsum    = offsets + 100032;                   // 512
    unsigned short* sub = (unsigned short*)(bsum + 512);
    // sub: GROUPS*BPG*R_PAD u16 = 8*48*12544*2 B = 9,633,792 B
    // byte offset of pairs: (100032+100032+512)*4 + 9633792 = 10,436,096 (8B-aligned)
    ull* pairs = (ull*)(sub + (size_t)GROUPS * BPG * R_PAD);

    gcn_gemm<<<(N_NODES + 255) / 256, 256, 0, stream>>>(x, w, support);
    k_count2<<<GROUPS * BPG, 256, 0, stream>>>(rows, sub);
    k_merge <<<SCAN1_BLOCKS, 256, 0, stream>>>(sub, counts);
    k_scan1 <<<SCAN1_BLOCKS, 256, 0, stream>>>(counts, offsets, bsum);
    k_scan2 <<<1, 512, 0, stream>>>(bsum);
    k_scan3 <<<SCAN1_BLOCKS, 256, 0, stream>>>(offsets, bsum);
    k_place2<<<GROUPS * BPG, 256, 0, stream>>>(rows, cols, vals, offsets, sub, pairs);
    k_rowsum<<<N_NODES / 4, 256, 0, stream>>>(offsets, counts, pairs, support, pa, out);
}

// Round 3
// 327.697 us; speedup vs baseline: 1.1319x; 1.1319x over previous
//
#include <hip/hip_runtime.h>

#define N_NODES 100000
#define N_EDGES 1600000
#define D_IN    128
#define D_OUT   64

#define SCAN1_BLOCKS 391        // ceil(100000/256)
#define XT_STRIDE 260           // padded row-count stride: 16B-aligned, low conflicts
#define GROUPS 8                // one row-range group per XCD
#define ROWS_PER_GROUP 12500    // 8 groups of 12500 rows
#define BPG 48                  // count blocks per group (slice count)
#define R_PAD 12544             // padded per-(group,block) row stride (even, 64-mult)
#define GCAP 212992             // per-group edge capacity (E/8=200000 +31 sigma, 256-mult)
#define PLACE_J 96              // place blocks per group
typedef unsigned long long ull;

// ---------------------------------------------------------------------------
// Kernel A: support = X @ W (fp32). Register-tiled LDS GEMM.
// ---------------------------------------------------------------------------
__global__ __launch_bounds__(256) void gcn_gemm(
    const float* __restrict__ x,        // [N, 128]
    const float* __restrict__ w,        // [128, 64]
    float* __restrict__ support)        // [N, 64]
{
    __shared__ float wl[D_IN * D_OUT];      // [k][col], 32 KB
    __shared__ float xT[32 * XT_STRIDE];    // [k_local][row], 33.3 KB

    const int t  = threadIdx.x;
    const int tx = t & 7;                   // col group
    const int ty = t >> 3;                  // row group
    const long row0 = (long)blockIdx.x * 256;

    {
        const float4* wf  = (const float4*)w;
        float4*       wlf = (float4*)wl;
#pragma unroll
        for (int j = 0; j < 8; ++j)
            wlf[t + 256 * j] = wf[t + 256 * j];
    }

    float acc[8][8];
#pragma unroll
    for (int i = 0; i < 8; ++i)
#pragma unroll
        for (int j = 0; j < 8; ++j)
            acc[i][j] = 0.f;

    for (int kc = 0; kc < 4; ++kc) {
        const int k0 = kc * 32;
        __syncthreads();

        const int kk = tx * 4;
#pragma unroll
        for (int it = 0; it < 8; ++it) {
            const int  rg   = it * 32 + ty;
            const long grow = row0 + rg;
            float4 v = make_float4(0.f, 0.f, 0.f, 0.f);
            if (grow < N_NODES)
                v = *(const float4*)&x[grow * D_IN + k0 + kk];
            xT[(kk + 0) * XT_STRIDE + rg] = v.x;
            xT[(kk + 1) * XT_STRIDE + rg] = v.y;
            xT[(kk + 2) * XT_STRIDE + rg] = v.z;
            xT[(kk + 3) * XT_STRIDE + rg] = v.w;
        }
        __syncthreads();

#pragma unroll 8
        for (int k = 0; k < 32; ++k) {
            const float4 a0 = *(const float4*)&xT[k * XT_STRIDE + ty * 8];
            const float4 a1 = *(const float4*)&xT[k * XT_STRIDE + ty * 8 + 4];
            const float4 b0 = *(const float4*)&wl[(k0 + k) * D_OUT + tx * 8];
            const float4 b1 = *(const float4*)&wl[(k0 + k) * D_OUT + tx * 8 + 4];
            const float av[8] = {a0.x, a0.y, a0.z, a0.w, a1.x, a1.y, a1.z, a1.w};
            const float bv[8] = {b0.x, b0.y, b0.z, b0.w, b1.x, b1.y, b1.z, b1.w};
#pragma unroll
            for (int i = 0; i < 8; ++i)
#pragma unroll
                for (int j = 0; j < 8; ++j)
                    acc[i][j] = fmaf(av[i], bv[j], acc[i][j]);
        }
    }

#pragma unroll
    for (int i = 0; i < 8; ++i) {
        const long r = row0 + ty * 8 + i;
        if (r < N_NODES) {
            float4 o0 = make_float4(acc[i][0], acc[i][1], acc[i][2], acc[i][3]);
            float4 o1 = make_float4(acc[i][4], acc[i][5], acc[i][6], acc[i][7]);
            *(float4*)&support[r * D_OUT + tx * 8]     = o0;
            *(float4*)&support[r * D_OUT + tx * 8 + 4] = o1;
        }
    }
}

// ---------------------------------------------------------------------------
// k_bin: read each edge ONCE; 8-way split by row group. Per 256-edge tile:
// LDS classify + compact, reserve per-group space with 8 global atomics
// (50K total, vs 1.6M per-edge atomics of round-1), write coalesced
// per-group segments of packed u64 (val:32 | r_local:14 | col:17).
// (Round-2 evidence: row-partitioned re-scan cost 8x rows re-reads, which
//  thrashed L2 and evicted partial pairs lines: FETCH 79MB, WRITE 64MB.)
// ---------------------------------------------------------------------------
__global__ __launch_bounds__(256) void k_bin(
    const int* __restrict__ rows, const int* __restrict__ cols,
    const float* __restrict__ vals, int* __restrict__ gcnt,
    ull* __restrict__ binned)
{
    __shared__ unsigned cnt[8], base_l[8], gbase[8];
    __shared__ ull buf[256];
    __shared__ unsigned char sg[256];
    const int t = threadIdx.x;

    for (int tile = blockIdx.x; tile * 256 < N_EDGES; tile += gridDim.x) {
        const int e = tile * 256 + t;                 // E%256==0 -> in bounds
        const int r = rows[e];
        const int g = r / ROWS_PER_GROUP;
        const unsigned rl = (unsigned)(r - g * ROWS_PER_GROUP);
        const ull p = ((ull)__float_as_uint(vals[e]) << 32)
                    | (rl << 17) | (unsigned)cols[e];

        if (t < 8) cnt[t] = 0;
        __syncthreads();
        const unsigned my = atomicAdd(&cnt[g], 1u);
        __syncthreads();
        if (t == 0) {
            unsigned run = 0;
#pragma unroll
            for (int i = 0; i < 8; ++i) { base_l[i] = run; run += cnt[i]; }
        }
        __syncthreads();
        if (t < 8) gbase[t] = atomicAdd((unsigned*)&gcnt[t], cnt[t]);
        const unsigned idx = base_l[g] + my;
        buf[idx] = p;
        sg[idx]  = (unsigned char)g;
        __syncthreads();
        const int g2 = sg[t];
        binned[(size_t)g2 * GCAP + gbase[g2] + (t - base_l[g2])] = buf[t];
        __syncthreads();                              // buf/base reuse next tile
    }
}

// ---------------------------------------------------------------------------
// k_count3: block (g,b) streams slice b of group g's COMPACT edge list
// (XCD-local, read once). Packed-u16 LDS histogram; the atomic return value
// is the edge's in-block rank -> lrank (coalesced u16 write). Zero global
// atomics.
// ---------------------------------------------------------------------------
__global__ __launch_bounds__(256) void k_count3(
    const ull* __restrict__ binned, const int* __restrict__ gcnt,
    unsigned short* __restrict__ sub, unsigned short* __restrict__ lrank)
{
    __shared__ unsigned hist[R_PAD / 2];    // 25.1 KB
    const int g    = blockIdx.x & 7;
    const int b    = blockIdx.x >> 3;
    const int size = gcnt[g];
    const ull* my  = &binned[(size_t)g * GCAP];
    unsigned short* mylr = &lrank[(size_t)g * GCAP];

    for (int i = threadIdx.x; i < R_PAD / 2; i += 256) hist[i] = 0u;
    __syncthreads();

    for (int base = b * 256; base < size; base += BPG * 256) {
        const int i = base + threadIdx.x;
        if (i < size) {
            const unsigned rl = ((unsigned)my[i] >> 17) & 0x3fffu;
            const unsigned sh = (rl & 1) * 16;
            const unsigned old = atomicAdd(&hist[rl >> 1], 1u << sh);
            mylr[i] = (unsigned short)((old >> sh) & 0xffffu);
        }
    }
    __syncthreads();

    unsigned* dst = (unsigned*)&sub[(size_t)(g * BPG + b) * R_PAD];
    for (int i = threadIdx.x; i < R_PAD / 2; i += 256) dst[i] = hist[i];
}

// ---------------------------------------------------------------------------
// k_merge: per row, exclusive prefix over the 48 per-block counts (in place)
// + total -> counts[r]. Writes ALL of counts[] (no memset needed).
// ---------------------------------------------------------------------------
__global__ __launch_bounds__(256) void k_merge(
    unsigned short* __restrict__ sub, int* __restrict__ counts)
{
    const int r = blockIdx.x * 256 + threadIdx.x;
    if (r >= N_NODES) return;
    const int g = r / ROWS_PER_GROUP;
    const int i = r - g * ROWS_PER_GROUP;
    unsigned short* col = &sub[(size_t)g * BPG * R_PAD + i];
    int run = 0;
#pragma unroll 4
    for (int b = 0; b < BPG; ++b) {
        const int v = col[(size_t)b * R_PAD];
        col[(size_t)b * R_PAD] = (unsigned short)run;
        run += v;
    }
    counts[r] = run;
}

// phase 1: per-block exclusive scan of counts -> offsets, block totals -> bsum
__global__ __launch_bounds__(256) void k_scan1(
    const int* __restrict__ counts, int* __restrict__ offsets,
    int* __restrict__ bsum)
{
    __shared__ int s[256];
    const int t = threadIdx.x;
    const int i = blockIdx.x * 256 + t;
    const int v = (i < N_NODES) ? counts[i] : 0;
    s[t] = v;
    __syncthreads();
#pragma unroll
    for (int off = 1; off < 256; off <<= 1) {
        const int add = (t >= off) ? s[t - off] : 0;
        __syncthreads();
        s[t] += add;
        __syncthreads();
    }
    if (i < N_NODES) offsets[i] = s[t] - v;          // exclusive
    if (t == 255) bsum[blockIdx.x] = s[255];
}

// phase 2: exclusive scan of 391 block sums (single block of 512)
__global__ __launch_bounds__(512) void k_scan2(int* __restrict__ bsum)
{
    __shared__ int s[512];
    const int t = threadIdx.x;
    const int v = (t < SCAN1_BLOCKS) ? bsum[t] : 0;
    s[t] = v;
    __syncthreads();
#pragma unroll
    for (int off = 1; off < 512; off <<= 1) {
        const int add = (t >= off) ? s[t - off] : 0;
        __syncthreads();
        s[t] += add;
        __syncthreads();
    }
    if (t < SCAN1_BLOCKS) bsum[t] = s[t] - v;        // exclusive
}

// phase 3: add block base
__global__ __launch_bounds__(256) void k_scan3(
    int* __restrict__ offsets, const int* __restrict__ bsum)
{
    const int i = blockIdx.x * 256 + threadIdx.x;
    if (i < N_NODES)
        offsets[i] += bsum[blockIdx.x];
}

// ---------------------------------------------------------------------------
// k_place3: NO LDS, NO atomics, full occupancy. pos = offsets[r] +
// sub[g][b][r] + lrank[i], with b = (i>>8)%48 reconstructing which count
// block handled index i (count slicing: i in [b*256 + k*BPG*256, +256)).
// Gathers are L2-hot (offsets: 50KB/group; sub: one 25KB panel per tile).
// blockIdx&7 = g keeps pairs writes XCD-grouped -> lines assemble in one L2.
// ---------------------------------------------------------------------------
__global__ __launch_bounds__(256) void k_place3(
    const ull* __restrict__ binned, const int* __restrict__ gcnt,
    const int* __restrict__ offsets, const unsigned short* __restrict__ sub,
    const unsigned short* __restrict__ lrank, ull* __restrict__ pairs)
{
    const int g    = blockIdx.x & 7;
    const int j    = blockIdx.x >> 3;
    const int size = gcnt[g];
    const int rlo  = g * ROWS_PER_GROUP;
    const ull* my  = &binned[(size_t)g * GCAP];
    const unsigned short* mylr = &lrank[(size_t)g * GCAP];

    for (int base = j * 256; base < size; base += PLACE_J * 256) {
        const int i = base + threadIdx.x;
        if (i < size) {
            const ull p = my[i];
            const unsigned lo = (unsigned)p;
            const unsigned rl = (lo >> 17) & 0x3fffu;
            const unsigned c  = lo & 0x1ffffu;
            const int b = (i >> 8) % BPG;
            const int pos = offsets[rlo + rl]
                          + (int)sub[(size_t)(g * BPG + b) * R_PAD + rl]
                          + (int)mylr[i];
            pairs[pos] = (p & 0xffffffff00000000ull) | c;
        }
    }
}

// ---------------------------------------------------------------------------
// Segmented row sum + fused PReLU. One wave per row, lane = column.
// ---------------------------------------------------------------------------
__global__ __launch_bounds__(256) void k_rowsum(
    const int* __restrict__ offsets, const int* __restrict__ counts,
    const ull* __restrict__ pairs, const float* __restrict__ support,
    const float* __restrict__ prelu_a, float* __restrict__ out)
{
    const int lane = threadIdx.x & 63;
    const int row  = blockIdx.x * 4 + (threadIdx.x >> 6);  // grid exact: N%4==0

    const int start = offsets[row];
    const int deg   = counts[row];

    float acc = 0.f;
    int j = 0;
    for (; j + 8 <= deg; j += 8) {
        ull p[8];
#pragma unroll
        for (int u = 0; u < 8; ++u) p[u] = pairs[start + j + u];
        float s[8];
#pragma unroll
        for (int u = 0; u < 8; ++u)
            s[u] = support[(size_t)(unsigned)(p[u] & 0x1ffffu) * D_OUT + lane];
#pragma unroll
        for (int u = 0; u < 8; ++u)
            acc = fmaf(__uint_as_float((unsigned)(p[u] >> 32)), s[u], acc);
    }
    for (; j + 4 <= deg; j += 4) {
        ull p[4];
#pragma unroll
        for (int u = 0; u < 4; ++u) p[u] = pairs[start + j + u];
        float s[4];
#pragma unroll
        for (int u = 0; u < 4; ++u)
            s[u] = support[(size_t)(unsigned)(p[u] & 0x1ffffu) * D_OUT + lane];
#pragma unroll
        for (int u = 0; u < 4; ++u)
            acc = fmaf(__uint_as_float((unsigned)(p[u] >> 32)), s[u], acc);
    }
    for (; j < deg; ++j) {
        const ull p = pairs[start + j];
        const float s = support[(size_t)(unsigned)(p & 0x1ffffu) * D_OUT + lane];
        acc = fmaf(__uint_as_float((unsigned)(p >> 32)), s, acc);
    }

    const float a = prelu_a[0];
    out[(size_t)row * D_OUT + lane] = acc > 0.f ? acc : a * acc;
}

// ---------------------------------------------------------------------------
extern "C" void kernel_launch(void* const* d_in, const int* in_sizes, int n_in,
                              void* d_out, int out_size, void* d_ws, size_t ws_size,
                              hipStream_t stream) {
    const float* x    = (const float*)d_in[0];
    const int*   rows = (const int*)d_in[1];
    const int*   cols = (const int*)d_in[2];
    const float* vals = (const float*)d_in[3];
    const float* w    = (const float*)d_in[4];
    const float* pa   = (const float*)d_in[5];

    float* out     = (float*)d_out;                    // [N*64] PReLU output
    float* support = out + (size_t)N_NODES * D_OUT;    // [N*64] support (tuple elem 1)

    // workspace layout (~38.4 MiB)
    int* gcnt    = (int*)d_ws;                         // 64 (8 used)
    int* counts  = gcnt    + 64;                       // 100032
    int* offsets = counts  + 100032;                   // 100032
    int* bsum    = offsets + 100032;                   // 512
    unsigned short* sub   = (unsigned short*)(bsum + 512);       // 8*48*12544
    unsigned short* lrank = sub + (size_t)GROUPS * BPG * R_PAD;  // 8*GCAP
    // byte offset of binned: (64+100032+100032+512)*4 + 9633792 + 8*GCAP*2
    //   = 802560 + 9633792 + 3407872 = 13,844,224 (8B-aligned)
    ull* binned = (ull*)(lrank + (size_t)GROUPS * GCAP);
    ull* pairs  = binned + (size_t)GROUPS * GCAP;

    hipMemsetAsync(gcnt, 0, 64 * sizeof(int), stream);

    gcn_gemm<<<(N_NODES + 255) / 256, 256, 0, stream>>>(x, w, support);
    k_bin   <<<2048, 256, 0, stream>>>(rows, cols, vals, gcnt, binned);
    k_count3<<<GROUPS * BPG, 256, 0, stream>>>(binned, gcnt, sub, lrank);
    k_merge <<<SCAN1_BLOCKS, 256, 0, stream>>>(sub, counts);
    k_scan1 <<<SCAN1_BLOCKS, 256, 0, stream>>>(counts, offsets, bsum);
    k_scan2 <<<1, 512, 0, stream>>>(bsum);
    k_scan3 <<<SCAN1_BLOCKS, 256, 0, stream>>>(offsets, bsum);
    k_place3<<<GROUPS * PLACE_J, 256, 0, stream>>>(binned, gcnt, offsets, sub, lrank, pairs);
    k_rowsum<<<N_NODES / 4, 256, 0, stream>>>(offsets, counts, pairs, support, pa, out);
}

// Round 4
// 297.027 us; speedup vs baseline: 1.2488x; 1.1033x over previous
//
#include <hip/hip_runtime.h>

#define N_NODES 100000
#define N_EDGES 1600000
#define D_IN    128
#define D_OUT   64

#define SCAN1_BLOCKS 391        // ceil(100000/256)
#define XT_STRIDE 260           // padded row-count stride: 16B-aligned, low conflicts
#define GROUPS 8                // one row-range group per XCD
#define ROWS_PER_GROUP 12500    // 8 groups of 12500 rows
#define BPG 48                  // count blocks per group (slice count)
#define R_PAD 12544             // padded per-(group,block) row stride (even, 64-mult)
#define GCAP 212992             // per-group edge capacity (E/8=200000 + 31 sigma)
#define PLACE_J 96              // place blocks per group
#define NTILES 6250             // N_EDGES / 256
#define BIN_SWZ 782             // ceil(NTILES/8) for XCD-chunked tile order
typedef unsigned long long ull;

// ---------------------------------------------------------------------------
// Kernel A: support = X @ W (fp32). Register-tiled LDS GEMM.
// ---------------------------------------------------------------------------
__global__ __launch_bounds__(256) void gcn_gemm(
    const float* __restrict__ x,        // [N, 128]
    const float* __restrict__ w,        // [128, 64]
    float* __restrict__ support)        // [N, 64]
{
    __shared__ float wl[D_IN * D_OUT];      // [k][col], 32 KB
    __shared__ float xT[32 * XT_STRIDE];    // [k_local][row], 33.3 KB

    const int t  = threadIdx.x;
    const int tx = t & 7;                   // col group
    const int ty = t >> 3;                  // row group
    const long row0 = (long)blockIdx.x * 256;

    {
        const float4* wf  = (const float4*)w;
        float4*       wlf = (float4*)wl;
#pragma unroll
        for (int j = 0; j < 8; ++j)
            wlf[t + 256 * j] = wf[t + 256 * j];
    }

    float acc[8][8];
#pragma unroll
    for (int i = 0; i < 8; ++i)
#pragma unroll
        for (int j = 0; j < 8; ++j)
            acc[i][j] = 0.f;

    for (int kc = 0; kc < 4; ++kc) {
        const int k0 = kc * 32;
        __syncthreads();

        const int kk = tx * 4;
#pragma unroll
        for (int it = 0; it < 8; ++it) {
            const int  rg   = it * 32 + ty;
            const long grow = row0 + rg;
            float4 v = make_float4(0.f, 0.f, 0.f, 0.f);
            if (grow < N_NODES)
                v = *(const float4*)&x[grow * D_IN + k0 + kk];
            xT[(kk + 0) * XT_STRIDE + rg] = v.x;
            xT[(kk + 1) * XT_STRIDE + rg] = v.y;
            xT[(kk + 2) * XT_STRIDE + rg] = v.z;
            xT[(kk + 3) * XT_STRIDE + rg] = v.w;
        }
        __syncthreads();

#pragma unroll 8
        for (int k = 0; k < 32; ++k) {
            const float4 a0 = *(const float4*)&xT[k * XT_STRIDE + ty * 8];
            const float4 a1 = *(const float4*)&xT[k * XT_STRIDE + ty * 8 + 4];
            const float4 b0 = *(const float4*)&wl[(k0 + k) * D_OUT + tx * 8];
            const float4 b1 = *(const float4*)&wl[(k0 + k) * D_OUT + tx * 8 + 4];
            const float av[8] = {a0.x, a0.y, a0.z, a0.w, a1.x, a1.y, a1.z, a1.w};
            const float bv[8] = {b0.x, b0.y, b0.z, b0.w, b1.x, b1.y, b1.z, b1.w};
#pragma unroll
            for (int i = 0; i < 8; ++i)
#pragma unroll
                for (int j = 0; j < 8; ++j)
                    acc[i][j] = fmaf(av[i], bv[j], acc[i][j]);
        }
    }

#pragma unroll
    for (int i = 0; i < 8; ++i) {
        const long r = row0 + ty * 8 + i;
        if (r < N_NODES) {
            float4 o0 = make_float4(acc[i][0], acc[i][1], acc[i][2], acc[i][3]);
            float4 o1 = make_float4(acc[i][4], acc[i][5], acc[i][6], acc[i][7]);
            *(float4*)&support[r * D_OUT + tx * 8]     = o0;
            *(float4*)&support[r * D_OUT + tx * 8 + 4] = o1;
        }
    }
}

// ---------------------------------------------------------------------------
// Binning, now FULLY deterministic -- zero atomics of any scope.
// (Round-3 evidence: k_bin at 76us with HBM 3.9%, VALU 1.4% -- stalled on
//  50K device-scope atomics all hitting ONE 32B line (gcnt[0..7]), i.e.
//  serialized line ping-pong at the coherence point, plus 533K LDS-atomic
//  bank conflicts. Replaced by ballot counting + explicit tile scan.)
//
// k_tilecount: one block per 256-edge tile; per-wave per-group counts via
// __ballot/__popcll (no atomics), one coalesced 32B line written per tile.
// ---------------------------------------------------------------------------
__global__ __launch_bounds__(256) void k_tilecount(
    const int* __restrict__ rows, unsigned* __restrict__ tc)
{
    __shared__ unsigned short cw[4][8];
    const int t = threadIdx.x, w = t >> 6, lane = t & 63;
    const int tile = blockIdx.x;
    const int g = rows[tile * 256 + t] / ROWS_PER_GROUP;
#pragma unroll
    for (int k = 0; k < 8; ++k) {
        const ull m = __ballot(g == k);
        if (lane == 0) cw[w][k] = (unsigned short)__popcll(m);
    }
    __syncthreads();
    if (t < 8)
        tc[(size_t)tile * 8 + t] =
            (unsigned)(cw[0][t] + cw[1][t] + cw[2][t] + cw[3][t]);
}

// ---------------------------------------------------------------------------
// k_tscan: 8 blocks; block g prefix-scans its group's 6250 tile counts in
// place (counts -> exclusive bases) and writes gcnt[g] (total per group).
// ---------------------------------------------------------------------------
__global__ __launch_bounds__(256) void k_tscan(
    unsigned* __restrict__ tc, int* __restrict__ gcnt)
{
    __shared__ unsigned s[256];
    const int g = blockIdx.x;
    const int t = threadIdx.x;
    unsigned run = 0;
    for (int base = 0; base < NTILES; base += 256) {
        const int i = base + t;
        const unsigned v = (i < NTILES) ? tc[(size_t)i * 8 + g] : 0u;
        s[t] = v;
        __syncthreads();
#pragma unroll
        for (int off = 1; off < 256; off <<= 1) {
            const unsigned add = (t >= off) ? s[t - off] : 0u;
            __syncthreads();
            s[t] += add;
            __syncthreads();
        }
        if (i < NTILES) tc[(size_t)i * 8 + g] = run + s[t] - v;
        run += s[255];
        __syncthreads();                    // protect s[] reuse next chunk
    }
    if (t == 0) gcnt[g] = (int)run;
}

// ---------------------------------------------------------------------------
// k_bin2: pure arithmetic scatter. slot = tilebase[tile][g] + (waves-before
// count) + (ballot rank within wave). Packed u64 (val:32 | r_local:14 |
// col:17). Tile->block XCD swizzle keeps consecutive tiles (= adjacent
// binned segments) on one L2, so partial pair-lines assemble locally.
// ---------------------------------------------------------------------------
__global__ __launch_bounds__(256) void k_bin2(
    const int* __restrict__ rows, const int* __restrict__ cols,
    const float* __restrict__ vals, const unsigned* __restrict__ tilebase,
    ull* __restrict__ binned)
{
    __shared__ unsigned short cw[4][8];
    const int jj = blockIdx.x >> 3, xc = blockIdx.x & 7;
    const int tile = xc * BIN_SWZ + jj;
    if (tile >= NTILES) return;             // uniform per block
    const int t = threadIdx.x, w = t >> 6, lane = t & 63;

    const int e = tile * 256 + t;           // E%256==0 -> in bounds
    const int r = rows[e];
    const int g = r / ROWS_PER_GROUP;
    const unsigned rl = (unsigned)(r - g * ROWS_PER_GROUP);
    const ull p = ((ull)__float_as_uint(vals[e]) << 32)
                | (rl << 17) | (unsigned)cols[e];

    ull mymask = 0;
#pragma unroll
    for (int k = 0; k < 8; ++k) {
        const ull m = __ballot(g == k);
        if (lane == 0) cw[w][k] = (unsigned short)__popcll(m);
        if (g == k) mymask = m;             // no dynamic reg indexing
    }
    __syncthreads();
    int wb = 0;
#pragma unroll
    for (int w2 = 0; w2 < 3; ++w2)
        if (w2 < w) wb += cw[w2][g];
    const int rank = __popcll(mymask & ((1ull << lane) - 1ull));
    const unsigned idx = tilebase[(size_t)tile * 8 + g] + (unsigned)(wb + rank);
    binned[(size_t)g * GCAP + idx] = p;
}

// ---------------------------------------------------------------------------
// k_count3: block (g,b) streams slice b of group g's COMPACT edge list.
// Packed-u16 LDS histogram; the LDS-atomic return value is the edge's
// in-block rank -> lrank (coalesced u16 write). Zero global atomics.
// ---------------------------------------------------------------------------
__global__ __launch_bounds__(256) void k_count3(
    const ull* __restrict__ binned, const int* __restrict__ gcnt,
    unsigned short* __restrict__ sub, unsigned short* __restrict__ lrank)
{
    __shared__ unsigned hist[R_PAD / 2];    // 25.1 KB
    const int g    = blockIdx.x & 7;
    const int b    = blockIdx.x >> 3;
    const int size = gcnt[g];
    const ull* my  = &binned[(size_t)g * GCAP];
    unsigned short* mylr = &lrank[(size_t)g * GCAP];

    for (int i = threadIdx.x; i < R_PAD / 2; i += 256) hist[i] = 0u;
    __syncthreads();

    for (int base = b * 256; base < size; base += BPG * 256) {
        const int i = base + threadIdx.x;
        if (i < size) {
            const unsigned rl = ((unsigned)my[i] >> 17) & 0x3fffu;
            const unsigned sh = (rl & 1) * 16;
            const unsigned old = atomicAdd(&hist[rl >> 1], 1u << sh);
            mylr[i] = (unsigned short)((old >> sh) & 0xffffu);
        }
    }
    __syncthreads();

    unsigned* dst = (unsigned*)&sub[(size_t)(g * BPG + b) * R_PAD];
    for (int i = threadIdx.x; i < R_PAD / 2; i += 256) dst[i] = hist[i];
}

// ---------------------------------------------------------------------------
// k_merge: per row, exclusive prefix over the 48 per-block counts (in place)
// + total -> counts[r]. Writes ALL of counts[] (no memset needed).
// ---------------------------------------------------------------------------
__global__ __launch_bounds__(256) void k_merge(
    unsigned short* __restrict__ sub, int* __restrict__ counts)
{
    const int r = blockIdx.x * 256 + threadIdx.x;
    if (r >= N_NODES) return;
    const int g = r / ROWS_PER_GROUP;
    const int i = r - g * ROWS_PER_GROUP;
    unsigned short* col = &sub[(size_t)g * BPG * R_PAD + i];
    int run = 0;
#pragma unroll 4
    for (int b = 0; b < BPG; ++b) {
        const int v = col[(size_t)b * R_PAD];
        col[(size_t)b * R_PAD] = (unsigned short)run;
        run += v;
    }
    counts[r] = run;
}

// phase 1: per-block exclusive scan of counts -> offsets, block totals -> bsum
__global__ __launch_bounds__(256) void k_scan1(
    const int* __restrict__ counts, int* __restrict__ offsets,
    int* __restrict__ bsum)
{
    __shared__ int s[256];
    const int t = threadIdx.x;
    const int i = blockIdx.x * 256 + t;
    const int v = (i < N_NODES) ? counts[i] : 0;
    s[t] = v;
    __syncthreads();
#pragma unroll
    for (int off = 1; off < 256; off <<= 1) {
        const int add = (t >= off) ? s[t - off] : 0;
        __syncthreads();
        s[t] += add;
        __syncthreads();
    }
    if (i < N_NODES) offsets[i] = s[t] - v;          // exclusive
    if (t == 255) bsum[blockIdx.x] = s[255];
}

// phase 2: exclusive scan of 391 block sums (single block of 512)
__global__ __launch_bounds__(512) void k_scan2(int* __restrict__ bsum)
{
    __shared__ int s[512];
    const int t = threadIdx.x;
    const int v = (t < SCAN1_BLOCKS) ? bsum[t] : 0;
    s[t] = v;
    __syncthreads();
#pragma unroll
    for (int off = 1; off < 512; off <<= 1) {
        const int add = (t >= off) ? s[t - off] : 0;
        __syncthreads();
        s[t] += add;
        __syncthreads();
    }
    if (t < SCAN1_BLOCKS) bsum[t] = s[t] - v;        // exclusive
}

// phase 3: add block base
__global__ __launch_bounds__(256) void k_scan3(
    int* __restrict__ offsets, const int* __restrict__ bsum)
{
    const int i = blockIdx.x * 256 + threadIdx.x;
    if (i < N_NODES)
        offsets[i] += bsum[blockIdx.x];
}

// ---------------------------------------------------------------------------
// k_place3: NO LDS, NO atomics, full occupancy. pos = offsets[r] +
// sub[g][b][r] + lrank[i], with b = (i>>8)%48 reconstructing which count
// block handled index i. blockIdx&7 = g keeps pairs writes XCD-grouped.
// ---------------------------------------------------------------------------
__global__ __launch_bounds__(256) void k_place3(
    const ull* __restrict__ binned, const int* __restrict__ gcnt,
    const int* __restrict__ offsets, const unsigned short* __restrict__ sub,
    const unsigned short* __restrict__ lrank, ull* __restrict__ pairs)
{
    const int g    = blockIdx.x & 7;
    const int j    = blockIdx.x >> 3;
    const int size = gcnt[g];
    const int rlo  = g * ROWS_PER_GROUP;
    const ull* my  = &binned[(size_t)g * GCAP];
    const unsigned short* mylr = &lrank[(size_t)g * GCAP];

    for (int base = j * 256; base < size; base += PLACE_J * 256) {
        const int i = base + threadIdx.x;
        if (i < size) {
            const ull p = my[i];
            const unsigned lo = (unsigned)p;
            const unsigned rl = (lo >> 17) & 0x3fffu;
            const unsigned c  = lo & 0x1ffffu;
            const int b = (i >> 8) % BPG;
            const int pos = offsets[rlo + rl]
                          + (int)sub[(size_t)(g * BPG + b) * R_PAD + rl]
                          + (int)mylr[i];
            pairs[pos] = (p & 0xffffffff00000000ull) | c;
        }
    }
}

// ---------------------------------------------------------------------------
// Segmented row sum + fused PReLU. One wave per row, lane = column.
// ---------------------------------------------------------------------------
__global__ __launch_bounds__(256) void k_rowsum(
    const int* __restrict__ offsets, const int* __restrict__ counts,
    const ull* __restrict__ pairs, const float* __restrict__ support,
    const float* __restrict__ prelu_a, float* __restrict__ out)
{
    const int lane = threadIdx.x & 63;
    const int row  = blockIdx.x * 4 + (threadIdx.x >> 6);  // grid exact: N%4==0

    const int start = offsets[row];
    const int deg   = counts[row];

    float acc = 0.f;
    int j = 0;
    for (; j + 8 <= deg; j += 8) {
        ull p[8];
#pragma unroll
        for (int u = 0; u < 8; ++u) p[u] = pairs[start + j + u];
        float s[8];
#pragma unroll
        for (int u = 0; u < 8; ++u)
            s[u] = support[(size_t)(unsigned)(p[u] & 0x1ffffu) * D_OUT + lane];
#pragma unroll
        for (int u = 0; u < 8; ++u)
            acc = fmaf(__uint_as_float((unsigned)(p[u] >> 32)), s[u], acc);
    }
    for (; j + 4 <= deg; j += 4) {
        ull p[4];
#pragma unroll
        for (int u = 0; u < 4; ++u) p[u] = pairs[start + j + u];
        float s[4];
#pragma unroll
        for (int u = 0; u < 4; ++u)
            s[u] = support[(size_t)(unsigned)(p[u] & 0x1ffffu) * D_OUT + lane];
#pragma unroll
        for (int u = 0; u < 4; ++u)
            acc = fmaf(__uint_as_float((unsigned)(p[u] >> 32)), s[u], acc);
    }
    for (; j < deg; ++j) {
        const ull p = pairs[start + j];
        const float s = support[(size_t)(unsigned)(p & 0x1ffffu) * D_OUT + lane];
        acc = fmaf(__uint_as_float((unsigned)(p >> 32)), s, acc);
    }

    const float a = prelu_a[0];
    out[(size_t)row * D_OUT + lane] = acc > 0.f ? acc : a * acc;
}

// ---------------------------------------------------------------------------
extern "C" void kernel_launch(void* const* d_in, const int* in_sizes, int n_in,
                              void* d_out, int out_size, void* d_ws, size_t ws_size,
                              hipStream_t stream) {
    const float* x    = (const float*)d_in[0];
    const int*   rows = (const int*)d_in[1];
    const int*   cols = (const int*)d_in[2];
    const float* vals = (const float*)d_in[3];
    const float* w    = (const float*)d_in[4];
    const float* pa   = (const float*)d_in[5];

    float* out     = (float*)d_out;                    // [N*64] PReLU output
    float* support = out + (size_t)N_NODES * D_OUT;    // [N*64] support (tuple elem 1)

    // workspace layout (~38.4 MiB, unchanged from round 3)
    int* gcnt    = (int*)d_ws;                         // 64 (8 used)
    int* counts  = gcnt    + 64;                       // 100032
    int* offsets = counts  + 100032;                   // 100032
    int* bsum    = offsets + 100032;                   // 512
    unsigned short* sub   = (unsigned short*)(bsum + 512);       // 8*48*12544
    unsigned short* lrank = sub + (size_t)GROUPS * BPG * R_PAD;  // 8*GCAP
    ull* binned = (ull*)(lrank + (size_t)GROUPS * GCAP);
    ull* pairs  = binned + (size_t)GROUPS * GCAP;
    // tilecnt (NTILES*8 u32 = 200KB) aliases the pairs region: it is dead
    // (consumed by k_bin2) before k_place3 writes pairs.
    unsigned* tilecnt = (unsigned*)pairs;

    gcn_gemm   <<<(N_NODES + 255) / 256, 256, 0, stream>>>(x, w, support);
    k_tilecount<<<NTILES, 256, 0, stream>>>(rows, tilecnt);
    k_tscan    <<<GROUPS, 256, 0, stream>>>(tilecnt, gcnt);
    k_bin2     <<<GROUPS * BIN_SWZ, 256, 0, stream>>>(rows, cols, vals, tilecnt, binned);
    k_count3   <<<GROUPS * BPG, 256, 0, stream>>>(binned, gcnt, sub, lrank);
    k_merge    <<<SCAN1_BLOCKS, 256, 0, stream>>>(sub, counts);
    k_scan1    <<<SCAN1_BLOCKS, 256, 0, stream>>>(counts, offsets, bsum);
    k_scan2    <<<1, 512, 0, stream>>>(bsum);
    k_scan3    <<<SCAN1_BLOCKS, 256, 0, stream>>>(offsets, bsum);
    k_place3   <<<GROUPS * PLACE_J, 256, 0, stream>>>(binned, gcnt, offsets, sub, lrank, pairs);
    k_rowsum   <<<N_NODES / 4, 256, 0, stream>>>(offsets, counts, pairs, support, pa, out);
}